// Round 2
// baseline (276.834 us; speedup 1.0000x reference)
//
#include <hip/hip_runtime.h>
#include <hip/hip_bf16.h>
#include <cstdint>
#include <cstddef>

typedef short short8 __attribute__((ext_vector_type(8)));
typedef float floatx4 __attribute__((ext_vector_type(4)));
typedef unsigned short u16;

__device__ __forceinline__ u16 f2bf(float f) {
    __hip_bfloat16 h = __float2bfloat16(f);
    return __builtin_bit_cast(u16, h);
}

__device__ __forceinline__ void gload_lds16(const void* g, void* l) {
    __builtin_amdgcn_global_load_lds(
        (const __attribute__((address_space(1))) void*)g,
        (__attribute__((address_space(3))) void*)l, 16, 0, 0);
}

// ---------------- fp32 -> bf16 elementwise ----------------
__global__ __launch_bounds__(256) void cvt_x(const float* __restrict__ in, u16* __restrict__ out, int n4) {
    int stride = gridDim.x * blockDim.x;
    for (int i = blockIdx.x * blockDim.x + threadIdx.x; i < n4; i += stride) {
        float4 v = ((const float4*)in)[i];
        ushort4 o;
        o.x = f2bf(v.x); o.y = f2bf(v.y); o.z = f2bf(v.z); o.w = f2bf(v.w);
        ((ushort4*)out)[i] = o;
    }
}

// ---------------- W[K][N] f32 -> Wt[N][K] bf16 ----------------
__global__ __launch_bounds__(256) void transpose_cvt(const float* __restrict__ W, u16* __restrict__ Wt,
                                                     int K, int N) {
    __shared__ float tile[32][33];
    int n0 = blockIdx.x * 32, k0 = blockIdx.y * 32;
    int tx = threadIdx.x & 31, ty = threadIdx.x >> 5;  // ty 0..7
    #pragma unroll
    for (int i = 0; i < 32; i += 8)
        tile[ty + i][tx] = W[(size_t)(k0 + ty + i) * N + n0 + tx];
    __syncthreads();
    #pragma unroll
    for (int i = 0; i < 32; i += 8)
        Wt[(size_t)(n0 + ty + i) * K + k0 + tx] = f2bf(tile[tx][ty + i]);
}

// ---------------- bf16 GEMM: C[M][N] = A[M][K] * Bt[N][K]^T ----------------
// 128x128 tile, BK=32, 256 threads (4 waves, 2x2), wave does 64x64 via 4x4 16x16x32 MFMA.
template <bool OUT_BF16>
__global__ __launch_bounds__(256) void gemm_bt(const u16* __restrict__ A, const u16* __restrict__ Bt,
                                               void* __restrict__ C, int M, int N, int K) {
    __shared__ u16 As[128 * 32];
    __shared__ u16 Bs[128 * 32];
    const int tid = threadIdx.x;
    const int lane = tid & 63, wid = tid >> 6;
    const int m0 = blockIdx.x * 128, n0 = blockIdx.y * 128;
    const int wr = wid >> 1, wc = wid & 1;

    floatx4 acc[4][4] = {};

    const int c0 = tid, c1 = tid + 256;
    const u16* Ab = A + (size_t)m0 * K;
    const u16* Bb = Bt + (size_t)n0 * K;
    const size_t off0 = (size_t)(c0 >> 2) * K + (size_t)(c0 & 3) * 8;
    const size_t off1 = (size_t)(c1 >> 2) * K + (size_t)(c1 & 3) * 8;
    u16* As0 = &As[(wid * 64) * 8];
    u16* As1 = &As[(wid * 64 + 256) * 8];
    u16* Bs0 = &Bs[(wid * 64) * 8];
    u16* Bs1 = &Bs[(wid * 64 + 256) * 8];

    for (int k0 = 0; k0 < K; k0 += 32) {
        gload_lds16(Ab + off0 + k0, As0);
        gload_lds16(Ab + off1 + k0, As1);
        gload_lds16(Bb + off0 + k0, Bs0);
        gload_lds16(Bb + off1 + k0, Bs1);
        __syncthreads();
        short8 af[4], bfr[4];
        const u16* AsW = &As[(wr * 64) * 32];
        const u16* BsW = &Bs[(wc * 64) * 32];
        #pragma unroll
        for (int i = 0; i < 4; i++)
            af[i] = *(const short8*)&AsW[(i * 16 + (lane & 15)) * 32 + (lane >> 4) * 8];
        #pragma unroll
        for (int j = 0; j < 4; j++)
            bfr[j] = *(const short8*)&BsW[(j * 16 + (lane & 15)) * 32 + (lane >> 4) * 8];
        #pragma unroll
        for (int i = 0; i < 4; i++) {
            #pragma unroll
            for (int j = 0; j < 4; j++)
                acc[i][j] = __builtin_amdgcn_mfma_f32_16x16x32_bf16(af[i], bfr[j], acc[i][j], 0, 0, 0);
        }
        __syncthreads();
    }

    const int cr = (lane >> 4) * 4, cc = lane & 15;
    #pragma unroll
    for (int i = 0; i < 4; i++) {
        #pragma unroll
        for (int j = 0; j < 4; j++) {
            int row = m0 + wr * 64 + i * 16 + cr;
            int col = n0 + wc * 64 + j * 16 + cc;
            #pragma unroll
            for (int r = 0; r < 4; r++) {
                float v = acc[i][j][r];
                if (OUT_BF16)
                    ((u16*)C)[(size_t)(row + r) * N + col] = f2bf(v);
                else
                    ((float*)C)[(size_t)(row + r) * N + col] = v;
            }
        }
    }
}

// ---------------- causal attention ----------------
// One block per (b,h). 256 threads = 4 waves. Q addressed as [B*T][1024], KV as [B*T][2048] bf16.
// Per wave: 16-row Q subtiles (st = wid, wid+4, wid+8, wid+12).
__global__ __launch_bounds__(256) void attn_kernel(const u16* __restrict__ Q, const u16* __restrict__ KV,
                                                   u16* __restrict__ Y) {
    constexpr int T = 256, HD = 1024;
    constexpr int KS = 72;   // Ks row stride (pad 8 -> break power-of-2 column stride)
    constexpr int VS = 264;  // Vt / Ps row stride
    __shared__ u16 Ks[256 * KS];
    __shared__ u16 Vt[64 * VS];
    __shared__ u16 Ps[4][16 * VS];

    const int tid = threadIdx.x, lane = tid & 63, wid = tid >> 6;
    const int b = blockIdx.x >> 4, h = blockIdx.x & 15;
    const size_t baseQ = (size_t)b * T * HD + (size_t)h * 64;
    const size_t baseKV = (size_t)b * T * 2048 + (size_t)h * 64;

    // stage K: KV[.., h*64 .. h*64+63] rows -> Ks[256][72] (full 64 cols per row!)
    {
        int r = tid >> 2, c = (tid & 3) * 8;
        #pragma unroll
        for (int p = 0; p < 4; p++) {
            int row = r + p * 64;
            const u16* src = &KV[baseKV + (size_t)row * 2048];
            *(short8*)&Ks[row * KS + c]      = *(const short8*)&src[c];
            *(short8*)&Ks[row * KS + c + 32] = *(const short8*)&src[c + 32];
        }
    }
    // stage Vt[d][t] = V[t][d]
    {
        int d = tid & 63;
        for (int p = 0; p < 64; p++) {
            int t = wid * 64 + p;
            Vt[d * VS + t] = KV[baseKV + (size_t)t * 2048 + 1024 + d];
        }
    }
    __syncthreads();

    const float c_exp = 0.125f * 1.44269504088896f;  // scale * log2(e)
    const int kc = lane & 15, qq = (lane >> 4) * 4;

    #pragma unroll 1
    for (int ii = 0; ii < 4; ii++) {
        const int st = wid + ii * 4;   // q subtile index 0..15 (wave-uniform)
        const int q0 = st * 16;

        short8 qf0, qf1;
        {
            const u16* qp = &Q[baseQ + (size_t)(q0 + kc) * HD + (lane >> 4) * 8];
            qf0 = *(const short8*)qp;
            qf1 = *(const short8*)(qp + 32);
        }

        floatx4 s[16];
        #pragma unroll
        for (int kt = 0; kt < 16; kt++) {
            if (kt > st) continue;
            const u16* kp = &Ks[(kt * 16 + kc) * KS + (lane >> 4) * 8];
            short8 kf0 = *(const short8*)kp;
            short8 kf1 = *(const short8*)(kp + 32);
            floatx4 z = {0.f, 0.f, 0.f, 0.f};
            z = __builtin_amdgcn_mfma_f32_16x16x32_bf16(qf0, kf0, z, 0, 0, 0);
            s[kt] = __builtin_amdgcn_mfma_f32_16x16x32_bf16(qf1, kf1, z, 0, 0, 0);
            if (kt == st) {
                #pragma unroll
                for (int r = 0; r < 4; r++)
                    if (kc > qq + r) s[kt][r] = -INFINITY;
            }
        }

        float mx[4] = {-1e30f, -1e30f, -1e30f, -1e30f};
        #pragma unroll
        for (int kt = 0; kt < 16; kt++) {
            if (kt > st) continue;
            #pragma unroll
            for (int r = 0; r < 4; r++) mx[r] = fmaxf(mx[r], s[kt][r]);
        }
        #pragma unroll
        for (int off = 1; off < 16; off <<= 1) {
            #pragma unroll
            for (int r = 0; r < 4; r++) mx[r] = fmaxf(mx[r], __shfl_xor(mx[r], off));
        }

        float sum[4] = {0.f, 0.f, 0.f, 0.f};
        u16* Pw = &Ps[wid][0];
        #pragma unroll
        for (int kt = 0; kt < 16; kt++) {
            if (kt > st) continue;
            #pragma unroll
            for (int r = 0; r < 4; r++) {
                float p = exp2f((s[kt][r] - mx[r]) * c_exp);
                sum[r] += p;
                Pw[(qq + r) * VS + kt * 16 + kc] = f2bf(p);
            }
        }
        if ((st & 1) == 0) {  // zero-pad P columns up to the 32-wide PV tile
            #pragma unroll
            for (int r = 0; r < 4; r++) Pw[(qq + r) * VS + (st + 1) * 16 + kc] = 0;
        }
        #pragma unroll
        for (int off = 1; off < 16; off <<= 1) {
            #pragma unroll
            for (int r = 0; r < 4; r++) sum[r] += __shfl_xor(sum[r], off);
        }

        const int n32 = (st + 2) >> 1;
        floatx4 y[4] = {};
        #pragma unroll
        for (int k3 = 0; k3 < 8; k3++) {
            if (k3 >= n32) continue;
            short8 pf = *(const short8*)&Pw[kc * VS + k3 * 32 + (lane >> 4) * 8];
            #pragma unroll
            for (int dt = 0; dt < 4; dt++) {
                short8 vf = *(const short8*)&Vt[(dt * 16 + kc) * VS + k3 * 32 + (lane >> 4) * 8];
                y[dt] = __builtin_amdgcn_mfma_f32_16x16x32_bf16(pf, vf, y[dt], 0, 0, 0);
            }
        }

        float rinv[4];
        #pragma unroll
        for (int r = 0; r < 4; r++) rinv[r] = 1.0f / sum[r];
        #pragma unroll
        for (int dt = 0; dt < 4; dt++) {
            #pragma unroll
            for (int r = 0; r < 4; r++)
                Y[baseQ + (size_t)(q0 + qq + r) * HD + dt * 16 + kc] = f2bf(y[dt][r] * rinv[r]);
        }
    }
}

extern "C" void kernel_launch(void* const* d_in, const int* in_sizes, int n_in,
                              void* d_out, int out_size, void* d_ws, size_t ws_size,
                              hipStream_t stream) {
    const float* x         = (const float*)d_in[0];
    const float* w_kv_down = (const float*)d_in[1];
    const float* w_kv_up   = (const float*)d_in[2];
    const float* w_q       = (const float*)d_in[3];
    const float* w_out     = (const float*)d_in[4];
    float* out = (float*)d_out;

    constexpr int Bb = 64, Tt = 256, Cc = 1024, HD = 1024, R = 128;
    constexpr int M = Bb * Tt;  // 16384

    char* ws = (char*)d_ws;
    auto alloc = [&](size_t bytes) {
        void* p = (void*)ws;
        ws += (bytes + 255) & ~(size_t)255;
        return p;
    };
    u16* xb      = (u16*)alloc((size_t)M * Cc * 2);
    u16* wkvd_t  = (u16*)alloc((size_t)R * Cc * 2);
    u16* wkvu_t  = (u16*)alloc((size_t)2 * HD * R * 2);
    u16* wq_t    = (u16*)alloc((size_t)HD * Cc * 2);
    u16* wo_t    = (u16*)alloc((size_t)Cc * HD * 2);
    u16* latentb = (u16*)alloc((size_t)M * R * 2);
    u16* kvb     = (u16*)alloc((size_t)M * 2 * HD * 2);
    u16* qb      = (u16*)alloc((size_t)M * HD * 2);
    u16* yb      = (u16*)alloc((size_t)M * HD * 2);

    cvt_x<<<2048, 256, 0, stream>>>(x, xb, M * Cc / 4);
    transpose_cvt<<<dim3(R / 32, Cc / 32), 256, 0, stream>>>(w_kv_down, wkvd_t, Cc, R);
    transpose_cvt<<<dim3(2 * HD / 32, R / 32), 256, 0, stream>>>(w_kv_up, wkvu_t, R, 2 * HD);
    transpose_cvt<<<dim3(HD / 32, Cc / 32), 256, 0, stream>>>(w_q, wq_t, Cc, HD);
    transpose_cvt<<<dim3(Cc / 32, HD / 32), 256, 0, stream>>>(w_out, wo_t, HD, Cc);

    // latent = x @ Wkv_down   (M x 128 x 1024)
    gemm_bt<true><<<dim3(M / 128, R / 128), 256, 0, stream>>>(xb, wkvd_t, latentb, M, R, Cc);
    // kv = latent @ Wkv_up    (M x 2048 x 128)
    gemm_bt<true><<<dim3(M / 128, 2 * HD / 128), 256, 0, stream>>>(latentb, wkvu_t, kvb, M, 2 * HD, R);
    // q = x @ Wq              (M x 1024 x 1024)
    gemm_bt<true><<<dim3(M / 128, HD / 128), 256, 0, stream>>>(xb, wq_t, qb, M, HD, Cc);
    // attention
    attn_kernel<<<Bb * 16, 256, 0, stream>>>(qb, kvb, yb);
    // out = y @ Wout          (M x 1024 x 1024)
    gemm_bt<false><<<dim3(M / 128, Cc / 128), 256, 0, stream>>>(yb, wo_t, out, M, Cc, HD);
}

// Round 3
// 275.444 us; speedup vs baseline: 1.0050x; 1.0050x over previous
//
#include <hip/hip_runtime.h>
#include <hip/hip_bf16.h>
#include <cstdint>
#include <cstddef>

typedef short short8 __attribute__((ext_vector_type(8)));
typedef float floatx4 __attribute__((ext_vector_type(4)));
typedef unsigned short u16;

__device__ __forceinline__ u16 f2bf(float f) {
    __hip_bfloat16 h = __float2bfloat16(f);
    return __builtin_bit_cast(u16, h);
}

__device__ __forceinline__ void gload_lds16(const void* g, void* l) {
    __builtin_amdgcn_global_load_lds(
        (const __attribute__((address_space(1))) void*)g,
        (__attribute__((address_space(3))) void*)l, 16, 0, 0);
}

// ---------------- fp32 -> bf16 elementwise ----------------
__global__ __launch_bounds__(256) void cvt_x(const float* __restrict__ in, u16* __restrict__ out, int n4) {
    int stride = gridDim.x * blockDim.x;
    for (int i = blockIdx.x * blockDim.x + threadIdx.x; i < n4; i += stride) {
        float4 v = ((const float4*)in)[i];
        ushort4 o;
        o.x = f2bf(v.x); o.y = f2bf(v.y); o.z = f2bf(v.z); o.w = f2bf(v.w);
        ((ushort4*)out)[i] = o;
    }
}

// ---------------- W[K][N] f32 -> Wt[N][K] bf16 ----------------
__global__ __launch_bounds__(256) void transpose_cvt(const float* __restrict__ W, u16* __restrict__ Wt,
                                                     int K, int N) {
    __shared__ float tile[32][33];
    int n0 = blockIdx.x * 32, k0 = blockIdx.y * 32;
    int tx = threadIdx.x & 31, ty = threadIdx.x >> 5;  // ty 0..7
    #pragma unroll
    for (int i = 0; i < 32; i += 8)
        tile[ty + i][tx] = W[(size_t)(k0 + ty + i) * N + n0 + tx];
    __syncthreads();
    #pragma unroll
    for (int i = 0; i < 32; i += 8)
        Wt[(size_t)(n0 + ty + i) * K + k0 + tx] = f2bf(tile[tx][ty + i]);
}

// ---------------- bf16 GEMM: C[M][N] = A[M][K] * Bt[N][K]^T ----------------
// MODE: 0 = f32 [M][N], 1 = bf16 [M][N], 2 = bf16 per-head packed [b][h][t][64],
//       3 = kv split: col<1024 -> K per-head packed; col>=1024 -> V transposed [b][h][d][t]
template <int MODE>
__global__ __launch_bounds__(256) void gemm_bt(const u16* __restrict__ A, const u16* __restrict__ Bt,
                                               void* __restrict__ C, int M, int N, int K) {
    __shared__ u16 As[128 * 32];
    __shared__ u16 Bs[128 * 32];
    const int tid = threadIdx.x;
    const int lane = tid & 63, wid = tid >> 6;
    const int m0 = blockIdx.x * 128, n0 = blockIdx.y * 128;
    const int wr = wid >> 1, wc = wid & 1;

    floatx4 acc[4][4] = {};

    const int c0 = tid, c1 = tid + 256;
    const u16* Ab = A + (size_t)m0 * K;
    const u16* Bb = Bt + (size_t)n0 * K;
    const size_t off0 = (size_t)(c0 >> 2) * K + (size_t)(c0 & 3) * 8;
    const size_t off1 = (size_t)(c1 >> 2) * K + (size_t)(c1 & 3) * 8;
    u16* As0 = &As[(wid * 64) * 8];
    u16* As1 = &As[(wid * 64 + 256) * 8];
    u16* Bs0 = &Bs[(wid * 64) * 8];
    u16* Bs1 = &Bs[(wid * 64 + 256) * 8];

    for (int k0 = 0; k0 < K; k0 += 32) {
        gload_lds16(Ab + off0 + k0, As0);
        gload_lds16(Ab + off1 + k0, As1);
        gload_lds16(Bb + off0 + k0, Bs0);
        gload_lds16(Bb + off1 + k0, Bs1);
        __syncthreads();
        short8 af[4], bfr[4];
        const u16* AsW = &As[(wr * 64) * 32];
        const u16* BsW = &Bs[(wc * 64) * 32];
        #pragma unroll
        for (int i = 0; i < 4; i++)
            af[i] = *(const short8*)&AsW[(i * 16 + (lane & 15)) * 32 + (lane >> 4) * 8];
        #pragma unroll
        for (int j = 0; j < 4; j++)
            bfr[j] = *(const short8*)&BsW[(j * 16 + (lane & 15)) * 32 + (lane >> 4) * 8];
        #pragma unroll
        for (int i = 0; i < 4; i++) {
            #pragma unroll
            for (int j = 0; j < 4; j++)
                acc[i][j] = __builtin_amdgcn_mfma_f32_16x16x32_bf16(af[i], bfr[j], acc[i][j], 0, 0, 0);
        }
        __syncthreads();
    }

    const int cr = (lane >> 4) * 4, cc = lane & 15;
    #pragma unroll
    for (int i = 0; i < 4; i++) {
        #pragma unroll
        for (int j = 0; j < 4; j++) {
            int row = m0 + wr * 64 + i * 16 + cr;
            int col = n0 + wc * 64 + j * 16 + cc;
            #pragma unroll
            for (int r = 0; r < 4; r++) {
                float v = acc[i][j][r];
                int rr = row + r;
                if (MODE == 0) {
                    ((float*)C)[(size_t)rr * N + col] = v;
                } else if (MODE == 1) {
                    ((u16*)C)[(size_t)rr * N + col] = f2bf(v);
                } else if (MODE == 2) {
                    int h = col >> 6, dd = col & 63;
                    ((u16*)C)[(((size_t)(rr >> 8) * 16 + h) * 256 + (rr & 255)) * 64 + dd] = f2bf(v);
                } else {
                    if (col < 1024) {
                        int h = col >> 6, dd = col & 63;
                        ((u16*)C)[(((size_t)(rr >> 8) * 16 + h) * 256 + (rr & 255)) * 64 + dd] = f2bf(v);
                    } else {
                        int d = col - 1024;
                        int h = d >> 6, dd = d & 63;
                        u16* vt = (u16*)C + (size_t)16384 * 1024;
                        vt[(((size_t)(rr >> 8) * 16 + h) * 64 + dd) * 256 + (rr & 255)] = f2bf(v);
                    }
                }
            }
        }
    }
}

// ---------------- causal attention ----------------
// One block per (b,h). 256 threads = 4 waves. Qh/Kh packed [b][h][t][64], Vtg packed [b][h][d][t].
// K fragments read straight from global (L2-resident, 32KB/head). V staged in LDS (padded).
// Per wave: 16-row Q subtiles (st = wid, wid+4, wid+8, wid+12).
__global__ __launch_bounds__(256) void attn_kernel(const u16* __restrict__ Qh, const u16* __restrict__ Kh,
                                                   const u16* __restrict__ Vtg, u16* __restrict__ Y) {
    constexpr int T = 256, HD = 1024;
    constexpr int VS = 264;  // Vt / Ps row stride (rows stay 16B-aligned)
    __shared__ __align__(16) u16 Vt[64 * VS];
    __shared__ __align__(16) u16 Ps[4][16 * VS];

    const int tid = threadIdx.x, lane = tid & 63, wid = tid >> 6;
    const int bh = blockIdx.x;
    const size_t base = (size_t)bh * (T * 64);  // 16384 elements per (b,h)
    const size_t baseY = (size_t)(bh >> 4) * T * HD + (size_t)(bh & 15) * 64;

    // stage Vt[d][t] from pre-transposed global (coalesced 16B chunks)
    {
        const u16* vsrc = Vtg + base;
        #pragma unroll
        for (int it = 0; it < 8; it++) {
            int idx = tid + it * 256;       // 0..2047
            int d = idx >> 5, t0 = (idx & 31) * 8;
            *(short8*)&Vt[d * VS + t0] = *(const short8*)&vsrc[d * 256 + t0];
        }
    }
    __syncthreads();

    const float c_exp = 0.125f * 1.44269504088896f;  // scale * log2(e)
    const int kc = lane & 15, qq = (lane >> 4) * 4, hi8 = (lane >> 4) * 8;
    const u16* kbase = Kh + base;
    const u16* qbase = Qh + base;

    #pragma unroll 1
    for (int ii = 0; ii < 4; ii++) {
        const int st = wid + ii * 4;   // q subtile index 0..15 (wave-uniform)
        const int q0 = st * 16;

        short8 qf0, qf1;
        {
            const u16* qp = &qbase[(size_t)(q0 + kc) * 64 + hi8];
            qf0 = *(const short8*)qp;
            qf1 = *(const short8*)(qp + 32);
        }

        floatx4 s[16];
        #pragma unroll
        for (int kt = 0; kt < 16; kt++) {
            if (kt > st) continue;
            const u16* kp = &kbase[(size_t)(kt * 16 + kc) * 64 + hi8];
            short8 kf0 = *(const short8*)kp;
            short8 kf1 = *(const short8*)(kp + 32);
            floatx4 z = {0.f, 0.f, 0.f, 0.f};
            z = __builtin_amdgcn_mfma_f32_16x16x32_bf16(qf0, kf0, z, 0, 0, 0);
            s[kt] = __builtin_amdgcn_mfma_f32_16x16x32_bf16(qf1, kf1, z, 0, 0, 0);
            if (kt == st) {
                #pragma unroll
                for (int r = 0; r < 4; r++)
                    if (kc > qq + r) s[kt][r] = -INFINITY;
            }
        }

        float mx[4] = {-1e30f, -1e30f, -1e30f, -1e30f};
        #pragma unroll
        for (int kt = 0; kt < 16; kt++) {
            if (kt > st) continue;
            #pragma unroll
            for (int r = 0; r < 4; r++) mx[r] = fmaxf(mx[r], s[kt][r]);
        }
        #pragma unroll
        for (int off = 1; off < 16; off <<= 1) {
            #pragma unroll
            for (int r = 0; r < 4; r++) mx[r] = fmaxf(mx[r], __shfl_xor(mx[r], off));
        }

        float sum[4] = {0.f, 0.f, 0.f, 0.f};
        u16* Pw = &Ps[wid][0];
        #pragma unroll
        for (int kt = 0; kt < 16; kt++) {
            if (kt > st) continue;
            #pragma unroll
            for (int r = 0; r < 4; r++) {
                float p = exp2f((s[kt][r] - mx[r]) * c_exp);
                sum[r] += p;
                Pw[(qq + r) * VS + kt * 16 + kc] = f2bf(p);
            }
        }
        if ((st & 1) == 0) {  // zero-pad P columns up to the 32-wide PV tile
            #pragma unroll
            for (int r = 0; r < 4; r++) Pw[(qq + r) * VS + (st + 1) * 16 + kc] = 0;
        }
        #pragma unroll
        for (int off = 1; off < 16; off <<= 1) {
            #pragma unroll
            for (int r = 0; r < 4; r++) sum[r] += __shfl_xor(sum[r], off);
        }

        const int n32 = (st + 2) >> 1;
        floatx4 y[4] = {};
        #pragma unroll
        for (int k3 = 0; k3 < 8; k3++) {
            if (k3 >= n32) continue;
            short8 pf = *(const short8*)&Pw[kc * VS + k3 * 32 + hi8];
            #pragma unroll
            for (int dt = 0; dt < 4; dt++) {
                short8 vf = *(const short8*)&Vt[(dt * 16 + kc) * VS + k3 * 32 + hi8];
                y[dt] = __builtin_amdgcn_mfma_f32_16x16x32_bf16(pf, vf, y[dt], 0, 0, 0);
            }
        }

        float rinv[4];
        #pragma unroll
        for (int r = 0; r < 4; r++) rinv[r] = 1.0f / sum[r];
        #pragma unroll
        for (int dt = 0; dt < 4; dt++) {
            #pragma unroll
            for (int r = 0; r < 4; r++)
                Y[baseY + (size_t)(q0 + qq + r) * HD + dt * 16 + kc] = f2bf(y[dt][r] * rinv[r]);
        }
    }
}

extern "C" void kernel_launch(void* const* d_in, const int* in_sizes, int n_in,
                              void* d_out, int out_size, void* d_ws, size_t ws_size,
                              hipStream_t stream) {
    const float* x         = (const float*)d_in[0];
    const float* w_kv_down = (const float*)d_in[1];
    const float* w_kv_up   = (const float*)d_in[2];
    const float* w_q       = (const float*)d_in[3];
    const float* w_out     = (const float*)d_in[4];
    float* out = (float*)d_out;

    constexpr int Bb = 64, Tt = 256, Cc = 1024, HD = 1024, R = 128;
    constexpr int M = Bb * Tt;  // 16384

    char* ws = (char*)d_ws;
    auto alloc = [&](size_t bytes) {
        void* p = (void*)ws;
        ws += (bytes + 255) & ~(size_t)255;
        return p;
    };
    u16* xb      = (u16*)alloc((size_t)M * Cc * 2);
    u16* wkvd_t  = (u16*)alloc((size_t)R * Cc * 2);
    u16* wkvu_t  = (u16*)alloc((size_t)2 * HD * R * 2);
    u16* wq_t    = (u16*)alloc((size_t)HD * Cc * 2);
    u16* wo_t    = (u16*)alloc((size_t)Cc * HD * 2);
    u16* latentb = (u16*)alloc((size_t)M * R * 2);
    u16* kvb     = (u16*)alloc((size_t)M * 2 * HD * 2);  // kh [b][h][t][64] then vt [b][h][d][t]
    u16* qh      = (u16*)alloc((size_t)M * HD * 2);      // per-head packed q
    u16* yb      = (u16*)alloc((size_t)M * HD * 2);

    u16* kh  = kvb;
    u16* vtg = kvb + (size_t)M * HD;

    cvt_x<<<2048, 256, 0, stream>>>(x, xb, M * Cc / 4);
    transpose_cvt<<<dim3(R / 32, Cc / 32), 256, 0, stream>>>(w_kv_down, wkvd_t, Cc, R);
    transpose_cvt<<<dim3(2 * HD / 32, R / 32), 256, 0, stream>>>(w_kv_up, wkvu_t, R, 2 * HD);
    transpose_cvt<<<dim3(HD / 32, Cc / 32), 256, 0, stream>>>(w_q, wq_t, Cc, HD);
    transpose_cvt<<<dim3(Cc / 32, HD / 32), 256, 0, stream>>>(w_out, wo_t, HD, Cc);

    // latent = x @ Wkv_down   (M x 128 x 1024), bf16 [M][128]
    gemm_bt<1><<<dim3(M / 128, R / 128), 256, 0, stream>>>(xb, wkvd_t, latentb, M, R, Cc);
    // kv = latent @ Wkv_up    (M x 2048 x 128) -> K per-head packed + V transposed
    gemm_bt<3><<<dim3(M / 128, 2 * HD / 128), 256, 0, stream>>>(latentb, wkvu_t, kvb, M, 2 * HD, R);
    // q = x @ Wq              (M x 1024 x 1024) -> per-head packed
    gemm_bt<2><<<dim3(M / 128, HD / 128), 256, 0, stream>>>(xb, wq_t, qh, M, HD, Cc);
    // attention
    attn_kernel<<<Bb * 16, 256, 0, stream>>>(qh, kh, vtg, yb);
    // out = y @ Wout          (M x 1024 x 1024), fp32 [M][1024]
    gemm_bt<0><<<dim3(M / 128, Cc / 128), 256, 0, stream>>>(yb, wo_t, out, M, Cc, HD);
}